// Round 6
// baseline (716.966 us; speedup 1.0000x reference)
//
#include <hip/hip_runtime.h>
#include <hip/hip_bf16.h>
#include <cstddef>

// z_e_x: [8,4096,512] fp32 -> BN=32768 rows; codebook: [8192,512] fp32.
// Outputs: codes [BN,512] fp32, zqx_tilde [BN,512] fp32, idx [BN] as fp32.
//
// Numerics (bit-exact-verified): ref dist = fl(x_sq + 2*fl(dot)), cb_sq
// vanishes under fp32 rounding; fl(dot) = sequential fp32 fma chain
// k=0..511 ascending; argmin = first index.
//
// bf16 MFMA computes approx dots; GEMM epilogue stores per-(row,128-code
// block) min + 64-bit pair-mask within blockmin+MARGIN; select expands
// candidates and rechecks with the EXACT fp32 chain -> bit-exact argmin.
//
// ROUND-6: round-5 evidence = warm-L3 replay identical duration; per-step
// time ~1.2-2k cyc vs ~310 cyc matrix work; 1-deep prefetch + vmcnt(0)
// drain in __syncthreads leaves ~54% stall. Fix (single variable): depth-2
// prefetch with 3-buffer LDS ring + counted s_waitcnt vmcnt(6) + raw
// s_barrier (never vmcnt(0) in the main loop; T4 recipe). Ledger: at each
// step's wait, outstanding = 12 (kc+1, kc+2); vmcnt(6) retires kc+1's 6
// loads; barrier publishes. WAR: buf[(kc+2)%3] last read at step kc-1,
// consumed before that step's barrier. Tail: step14 vmcnt(0), step15 bare.
constexpr int BN   = 32768;
constexpr int DDIM = 512;
constexpr int KC   = 8192;
#define MARGIN 3.0e-4f

typedef __attribute__((ext_vector_type(8))) short short8;    // 8 bf16
typedef __attribute__((ext_vector_type(4))) float f32x4;

__device__ inline int fsw(int m) { return (m + (m >> 2)) & 3; }

__device__ inline unsigned short bf16_rne(float f) {
  unsigned u = __builtin_bit_cast(unsigned, f);
  unsigned r = u + 0x7FFFu + ((u >> 16) & 1u);
  return (unsigned short)(r >> 16);
}

#define GLL16(gp, lp)                                                         \
  __builtin_amdgcn_global_load_lds(                                           \
      (const __attribute__((address_space(1))) unsigned int*)(gp),            \
      (__attribute__((address_space(3))) unsigned int*)(lp), 16, 0, 0)

// ---------------- fused: X fp32 -> bf16 + per-row squared norm -------------
// Summation order identical to the verified vq_xsq -> bit-identical xsq.
__global__ __launch_bounds__(256) void vq_xcvt(const float* __restrict__ X,
                                               unsigned short* __restrict__ Xb,
                                               float* __restrict__ xsq) {
  const int wave = threadIdx.x >> 6;
  const int lane = threadIdx.x & 63;
  const int row = blockIdx.x * 4 + wave;
  const float4* r = (const float4*)(X + (size_t)row * DDIM);
  ushort4* ob = (ushort4*)(Xb + (size_t)row * DDIM);
  float s = 0.f;
#pragma unroll
  for (int t = 0; t < 2; ++t) {
    float4 v = r[lane + 64 * t];
    s += v.x * v.x + v.y * v.y + v.z * v.z + v.w * v.w;
    ushort4 o;
    o.x = bf16_rne(v.x); o.y = bf16_rne(v.y);
    o.z = bf16_rne(v.z); o.w = bf16_rne(v.w);
    ob[lane + 64 * t] = o;
  }
#pragma unroll
  for (int m = 32; m > 0; m >>= 1) s += __shfl_xor(s, m, 64);
  if (lane == 0) xsq[row] = s;
}

// ---------------- per-row squared norms (fallback path only) ----------------
__global__ __launch_bounds__(256) void vq_xsq(const float* __restrict__ X,
                                              float* __restrict__ xsq) {
  const int wave = threadIdx.x >> 6;
  const int lane = threadIdx.x & 63;
  const int row = blockIdx.x * 4 + wave;
  const float4* r = (const float4*)(X + (size_t)row * DDIM);
  float s = 0.f;
#pragma unroll
  for (int t = 0; t < 2; ++t) {
    float4 v = r[lane + 64 * t];
    s += v.x * v.x + v.y * v.y + v.z * v.z + v.w * v.w;
  }
#pragma unroll
  for (int m = 32; m > 0; m >>= 1) s += __shfl_xor(s, m, 64);
  if (lane == 0) xsq[row] = s;
}

// ---------------- fp32 -> bf16 convert (RNE), used for CB ----------------
__global__ __launch_bounds__(256) void vq_cvt(const float* __restrict__ src,
                                              unsigned short* __restrict__ dst,
                                              int n4) {
  int i = blockIdx.x * 256 + threadIdx.x;
  const int stride = gridDim.x * 256;
  for (; i < n4; i += stride) {
    float4 v = ((const float4*)src)[i];
    ushort4 o;
    o.x = bf16_rne(v.x); o.y = bf16_rne(v.y);
    o.z = bf16_rne(v.z); o.w = bf16_rne(v.w);
    ((ushort4*)dst)[i] = o;
  }
}

// -- bf16 MFMA GEMM, 128x256 tile, depth-2 prefetch (counted vmcnt), ------
// -- wave-private epilogue. 256 thr = 4 waves: wr=w>>1, wc=w&1. ------------
// Wave output: rows wr*64+[0,64), cols wc*128+[0,128) = ONE BM block.
// LDS ring: As[3][8192] (128r x 64B), Bs[3][16384] (256r x 64B), buf kc%3.
// Row layout: 32 bf16 = 4 quarters of 16B; physical quarter = q ^ fsw(row).
// Per step kc: STAGE(buf[(kc+2)%3], kc+2) -> compute buf[kc%3] ->
// s_waitcnt vmcnt(6) (kc+1's 6 loads done; kc+2's may fly) -> s_barrier.
__global__ __launch_bounds__(256, 2) void vq_gemmw(const unsigned short* __restrict__ Xb,
                                                   const unsigned short* __restrict__ CBb,
                                                   float* __restrict__ BM,
                                                   unsigned int* __restrict__ Msk) {
  __shared__ __align__(16) unsigned char As[3][8192];
  __shared__ __align__(16) unsigned char Bs[3][16384];
  __shared__ unsigned int mskW[4][64][2];

  const int tid  = threadIdx.x;
  const int lane = tid & 63;
  const int w    = tid >> 6;
  const int wr   = w >> 1, wc = w & 1;
  const int row0 = blockIdx.x * 128;
  const int col0 = blockIdx.y * 256;
  const int quad = lane >> 4, c16 = lane & 15;

  // per-lane staging sources (A: 2 granules, B: 4 granules of 16 rows)
  const int mloc = lane >> 2, qp = lane & 3;
  const int gA0 = 2 * w, gA1 = 2 * w + 1;
  const int maA0 = gA0 * 16 + mloc, maA1 = gA1 * 16 + mloc;
  const unsigned char* pA0 = (const unsigned char*)Xb +
      (size_t)(row0 + maA0) * 1024 + (size_t)((qp ^ fsw(maA0)) * 16);
  const unsigned char* pA1 = (const unsigned char*)Xb +
      (size_t)(row0 + maA1) * 1024 + (size_t)((qp ^ fsw(maA1)) * 16);
  const unsigned char* pBs[4];
#pragma unroll
  for (int g = 0; g < 4; ++g) {
    int ma = (4 * w + g) * 16 + mloc;
    pBs[g] = (const unsigned char*)CBb +
        (size_t)(col0 + ma) * 1024 + (size_t)((qp ^ fsw(ma)) * 16);
  }

  f32x4 acc[4][8];
#pragma unroll
  for (int i = 0; i < 4; ++i)
#pragma unroll
    for (int j = 0; j < 8; ++j) acc[i][j] = (f32x4)0.f;

#define STAGEW(BUF, KC_)                                                      \
  do {                                                                        \
    const size_t ko_ = (size_t)(KC_) * 64;                                    \
    GLL16(pA0 + ko_, As[BUF] + gA0 * 1024);                                   \
    GLL16(pA1 + ko_, As[BUF] + gA1 * 1024);                                   \
    GLL16(pBs[0] + ko_, Bs[BUF] + (4 * w + 0) * 1024);                        \
    GLL16(pBs[1] + ko_, Bs[BUF] + (4 * w + 1) * 1024);                        \
    GLL16(pBs[2] + ko_, Bs[BUF] + (4 * w + 2) * 1024);                        \
    GLL16(pBs[3] + ko_, Bs[BUF] + (4 * w + 3) * 1024);                        \
  } while (0)

#define VMC6 asm volatile("s_waitcnt vmcnt(6)" ::: "memory")
#define VMC0 asm volatile("s_waitcnt vmcnt(0)" ::: "memory")
#define BARX __builtin_amdgcn_s_barrier()
#define SB0  __builtin_amdgcn_sched_barrier(0)

  // prologue: stage steps 0 and 1 (12 outstanding); wait for step 0's 6.
  STAGEW(0, 0);
  STAGEW(1, 1);
  VMC6; BARX; SB0;

#pragma unroll
  for (int kc = 0; kc < 16; ++kc) {
    const int cur = kc % 3;
    if (kc + 2 <= 15) STAGEW((kc + 2) % 3, kc + 2);

    short8 a[4], b[8];
#pragma unroll
    for (int i = 0; i < 4; ++i) {
      int m = wr * 64 + i * 16 + c16;
      a[i] = *(const short8*)(As[cur] + m * 64 + ((quad ^ fsw(m)) * 16));
    }
#pragma unroll
    for (int j = 0; j < 8; ++j) {
      int n = wc * 128 + j * 16 + c16;
      b[j] = *(const short8*)(Bs[cur] + n * 64 + ((quad ^ fsw(n)) * 16));
    }
#pragma unroll
    for (int i = 0; i < 4; ++i)
#pragma unroll
      for (int j = 0; j < 8; ++j)
        acc[i][j] = __builtin_amdgcn_mfma_f32_16x16x32_bf16(a[i], b[j], acc[i][j], 0, 0, 0);

    if (kc + 2 <= 15)      { VMC6; BARX; SB0; }   // kc+1's loads landed
    else if (kc == 14)     { VMC0; BARX; SB0; }   // last buffer (15) landed
    // kc == 15: nothing outstanding; epilogue is wave-private.
  }

  // ---- wave-private epilogue: this wave's 64 rows x its 128-col BM block.
  // C/D layout: col = c16, row-in-frag = quad*4 + reg (learn_hip m89).
  mskW[w][lane][0] = 0u;
  mskW[w][lane][1] = 0u;
  asm volatile("s_waitcnt lgkmcnt(0)" ::: "memory");

  float vloc[4][4];
#pragma unroll
  for (int i = 0; i < 4; ++i)
#pragma unroll
    for (int reg = 0; reg < 4; ++reg) {
      float v = acc[i][0][reg];
#pragma unroll
      for (int j = 1; j < 8; ++j) v = fminf(v, acc[i][j][reg]);
#pragma unroll
      for (int m = 1; m < 16; m <<= 1) v = fminf(v, __shfl_xor(v, m, 64));
      vloc[i][reg] = v;
      float thr = v + MARGIN;
#pragma unroll
      for (int j = 0; j < 8; ++j) {
        if (acc[i][j][reg] <= thr) {
          int cl = j * 16 + c16;              // col in BM block, 0..127
          int p = cl >> 1;                    // pair 0..63
          int r = i * 16 + quad * 4 + reg;    // row in wave, 0..63
          atomicOr(&mskW[w][r][p >> 5], 1u << (p & 31));
        }
      }
    }
  asm volatile("s_waitcnt lgkmcnt(0)" ::: "memory");

  if (c16 == 0) {
#pragma unroll
    for (int i = 0; i < 4; ++i)
#pragma unroll
      for (int reg = 0; reg < 4; ++reg) {
        int r = i * 16 + quad * 4 + reg;
        int grow = row0 + wr * 64 + r;
        size_t o = (size_t)grow * 64 + (size_t)blockIdx.y * 2 + wc;
        BM[o]          = vloc[i][reg];
        Msk[o * 2 + 0] = mskW[w][r][0];
        Msk[o * 2 + 1] = mskW[w][r][1];
      }
  }
}

// -------- candidate expansion + exact fp32 recheck + fused gather ---------
// X row staged in LDS by the whole wave (coalesced); serial exact chain
// reads X from LDS and CB from global with unroll 8. Bit-exact.
__global__ __launch_bounds__(256) void vq_select(const float* __restrict__ X,
                                                 const float* __restrict__ CB,
                                                 const float* __restrict__ xsq,
                                                 const float* __restrict__ BM,
                                                 const unsigned int* __restrict__ Msk,
                                                 float* __restrict__ idx_f,
                                                 float* __restrict__ out_codes,
                                                 float* __restrict__ out_zqx) {
  __shared__ float xrow[4][DDIM];          // 8 KB: per-wave staged X row
  __shared__ unsigned short cand[4][128];
  __shared__ int cnt[4];
  const int lane = threadIdx.x & 63;
  const int w    = threadIdx.x >> 6;
  const int row  = blockIdx.x * 4 + w;

  if (lane == 0) cnt[w] = 0;

  // cooperative X-row stage (coalesced: 64 lanes x 2 float4)
  const float4* xr = (const float4*)(X + (size_t)row * DDIM);
  float4* xl4 = (float4*)xrow[w];
  xl4[lane]      = xr[lane];
  xl4[lane + 64] = xr[lane + 64];
  __syncthreads();

  const size_t bo = (size_t)row * 64 + lane;
  float bmv = BM[bo];
  float g = bmv;
#pragma unroll
  for (int m = 1; m < 64; m <<= 1) g = fminf(g, __shfl_xor(g, m, 64));
  if (bmv <= g + MARGIN) {
    unsigned m0 = Msk[bo * 2 + 0], m1 = Msk[bo * 2 + 1];
    while (m0) {
      int p = __ffs(m0) - 1; m0 &= m0 - 1;
      int base = lane * 128 + p * 2;
      int o = atomicAdd(&cnt[w], 2);
      if (o + 1 < 128) { cand[w][o] = (unsigned short)base; cand[w][o + 1] = (unsigned short)(base + 1); }
    }
    while (m1) {
      int p = __ffs(m1) - 1; m1 &= m1 - 1;
      int base = lane * 128 + 64 + p * 2;
      int o = atomicAdd(&cnt[w], 2);
      if (o + 1 < 128) { cand[w][o] = (unsigned short)base; cand[w][o + 1] = (unsigned short)(base + 1); }
    }
  }
  __syncthreads();

  int n = cnt[w]; n = n > 128 ? 128 : n;
  float bd = __builtin_inff();
  int   bi = 0x7fffffff;
  const float4* xl = (const float4*)xrow[w];
  const float   xs = xsq[row];
  for (int c = lane; c < n; c += 64) {
    int code = cand[w][c];
    const float4* cr = (const float4*)(CB + (size_t)code * DDIM);
    float acc = 0.f;   // EXACT chain: k ascending, single fp32 fma accumulator
#pragma unroll 8
    for (int k = 0; k < 128; ++k) {
      float4 xv = xl[k], cv = cr[k];
      acc = fmaf(xv.x, cv.x, acc);
      acc = fmaf(xv.y, cv.y, acc);
      acc = fmaf(xv.z, cv.z, acc);
      acc = fmaf(xv.w, cv.w, acc);
    }
    float d = fmaf(2.f, acc, xs);
    if (d < bd || (d == bd && code < bi)) { bd = d; bi = code; }
  }
#pragma unroll
  for (int m = 1; m < 64; m <<= 1) {
    float od = __shfl_xor(bd, m, 64);
    int   oi = __shfl_xor(bi, m, 64);
    if (od < bd || (od == bd && oi < bi)) { bd = od; bi = oi; }
  }
  if (lane == 0) idx_f[row] = (float)bi;
  // fused gather: bi is uniform across the wave after the butterfly
  const float4* cr2 = (const float4*)(CB + (size_t)bi * DDIM);
  float4* oc = (float4*)(out_codes + (size_t)row * DDIM);
  float4* oz = (float4*)(out_zqx   + (size_t)row * DDIM);
#pragma unroll
  for (int t = 0; t < 2; ++t) {
    float4 v = cr2[lane + 64 * t];
    oc[lane + 64 * t] = v;
    oz[lane + 64 * t] = v;
  }
}

// ---------------- gather (fallback path only) ----------------
__global__ __launch_bounds__(256) void vq_gather(const float* __restrict__ CB,
                                                 const int* __restrict__ idx_i,
                                                 float* __restrict__ out_codes,
                                                 float* __restrict__ out_zqx) {
  const int t = threadIdx.x;
  const int r = blockIdx.x * 2 + (t >> 7);
  const int q = t & 127;
  const int k = idx_i[r];
  float4 v = *(const float4*)(CB + (size_t)k * DDIM + q * 4);
  *(float4*)(out_codes + (size_t)r * DDIM + q * 4) = v;
  *(float4*)(out_zqx   + (size_t)r * DDIM + q * 4) = v;
}

// ---------------- fallback: fp32 fused GEMM+argmin (known-good) ----
constexpr int FMT = 64, FNT = 128, FDC = 32;
constexpr int FAS = FMT + 2, FBS = FNT + 2;
__global__ __launch_bounds__(256, 2) void vq_argmin_fb(const float* __restrict__ X,
                                                       const float* __restrict__ CB,
                                                       const float* __restrict__ xsq,
                                                       int* __restrict__ idx_i,
                                                       float* __restrict__ idx_f) {
  __shared__ float As[FDC][FAS];
  __shared__ float Bs[FDC][FBS];
  const int tid = threadIdx.x;
  const int tx = tid & 15, ty = tid >> 4;
  const int row_base = blockIdx.x * FMT;
  float xs[4];
#pragma unroll
  for (int i = 0; i < 4; ++i) xs[i] = xsq[row_base + ty * 4 + i];
  float bestv[4]; int besti[4];
#pragma unroll
  for (int i = 0; i < 4; ++i) { bestv[i] = __builtin_inff(); besti[i] = 0; }
  for (int c0 = 0; c0 < KC; c0 += FNT) {
    float acc[4][8];
#pragma unroll
    for (int i = 0; i < 4; ++i)
#pragma unroll
      for (int j = 0; j < 8; ++j) acc[i][j] = 0.f;
    for (int d0 = 0; d0 < DDIM; d0 += FDC) {
      __syncthreads();
#pragma unroll
      for (int s = 0; s < 2; ++s) {
        int f = tid + 256 * s; int r = f >> 3, q = f & 7;
        float4 v = *(const float4*)(X + (size_t)(row_base + r) * DDIM + d0 + q * 4);
        As[q * 4 + 0][r] = v.x; As[q * 4 + 1][r] = v.y;
        As[q * 4 + 2][r] = v.z; As[q * 4 + 3][r] = v.w;
      }
#pragma unroll
      for (int s = 0; s < 4; ++s) {
        int f = tid + 256 * s; int r = f >> 3, q = f & 7;
        float4 v = *(const float4*)(CB + (size_t)(c0 + r) * DDIM + d0 + q * 4);
        Bs[q * 4 + 0][r] = v.x; Bs[q * 4 + 1][r] = v.y;
        Bs[q * 4 + 2][r] = v.z; Bs[q * 4 + 3][r] = v.w;
      }
      __syncthreads();
#pragma unroll
      for (int kk = 0; kk < FDC; ++kk) {
        float a[4], b[8];
        *(float2*)&a[0] = *(const float2*)&As[kk][ty * 4 + 0];
        *(float2*)&a[2] = *(const float2*)&As[kk][ty * 4 + 2];
        *(float2*)&b[0] = *(const float2*)&Bs[kk][tx * 4 + 0];
        *(float2*)&b[2] = *(const float2*)&Bs[kk][tx * 4 + 2];
        *(float2*)&b[4] = *(const float2*)&Bs[kk][64 + tx * 4 + 0];
        *(float2*)&b[6] = *(const float2*)&Bs[kk][64 + tx * 4 + 2];
#pragma unroll
        for (int i = 0; i < 4; ++i)
#pragma unroll
          for (int j = 0; j < 8; ++j) acc[i][j] = fmaf(a[i], b[j], acc[i][j]);
      }
    }
#pragma unroll
    for (int j = 0; j < 8; ++j) {
      int c = c0 + ((j < 4) ? (tx * 4 + j) : (64 + tx * 4 + (j - 4)));
#pragma unroll
      for (int i = 0; i < 4; ++i) {
        float d = fmaf(2.f, acc[i][j], xs[i]);
        if (d < bestv[i] || (d == bestv[i] && c < besti[i])) { bestv[i] = d; besti[i] = c; }
      }
    }
  }
#pragma unroll
  for (int m = 1; m < 16; m <<= 1) {
#pragma unroll
    for (int i = 0; i < 4; ++i) {
      float ov = __shfl_xor(bestv[i], m, 64);
      int   oi = __shfl_xor(besti[i], m, 64);
      if (ov < bestv[i] || (ov == bestv[i] && oi < besti[i])) { bestv[i] = ov; besti[i] = oi; }
    }
  }
  if (tx == 0) {
#pragma unroll
    for (int i = 0; i < 4; ++i) {
      int r = row_base + ty * 4 + i;
      idx_i[r] = besti[i];
      idx_f[r] = (float)besti[i];
    }
  }
}

extern "C" void kernel_launch(void* const* d_in, const int* in_sizes, int n_in,
                              void* d_out, int out_size, void* d_ws, size_t ws_size,
                              hipStream_t stream) {
  const float* X  = (const float*)d_in[0];
  const float* CB = (const float*)d_in[1];

  float* out       = (float*)d_out;
  float* out_codes = out;
  float* out_zqx   = out + (size_t)BN * DDIM;
  float* out_idxf  = out + 2 * (size_t)BN * DDIM;

  unsigned char* w0 = (unsigned char*)d_ws;
  const size_t NEED = (64ull << 20) + 2 * (size_t)BN * 4;

  if (ws_size >= NEED) {
    unsigned short* Xb  = (unsigned short*)w0;                    // 32 MB
    unsigned short* CBb = (unsigned short*)(w0 + (32ull << 20));  //  8 MB
    float*        BM    = (float*)(w0 + (40ull << 20));           //  8 MB
    unsigned int* Msk   = (unsigned int*)(w0 + (48ull << 20));    // 16 MB
    float*        xsq   = (float*)(w0 + (64ull << 20));

    vq_xcvt  <<<BN / 4, 256, 0, stream>>>(X, Xb, xsq);
    vq_cvt   <<<128, 256, 0, stream>>>(CB, CBb, KC * (DDIM / 4));
    vq_gemmw <<<dim3(BN / 128, KC / 256), 256, 0, stream>>>(Xb, CBb, BM, Msk);
    vq_select<<<BN / 4, 256, 0, stream>>>(X, CB, xsq, BM, Msk, out_idxf,
                                          out_codes, out_zqx);
  } else {
    float* xsq   = (float*)w0;
    int*   idx_i = (int*)(w0 + (size_t)BN * 4);
    vq_xsq      <<<BN / 4, 256, 0, stream>>>(X, xsq);
    vq_argmin_fb<<<BN / FMT, 256, 0, stream>>>(X, CB, xsq, idx_i, out_idxf);
    vq_gather   <<<BN / 2, 256, 0, stream>>>(CB, idx_i, out_codes, out_zqx);
  }
}